// Round 1
// baseline (621.164 us; speedup 1.0000x reference)
//
#include <hip/hip_runtime.h>
#include <hip/hip_bf16.h>

// Grouped GEMM: out[e] = x[e] @ W[e]^T
//   x: [8, 4096, 128] fp32, W: [8, 4096, 128] fp32 -> out: [8, 4096, 4096] fp32
// Write-bound (537 MB out vs 34.4 GFLOP). Strategy: in-kernel fp32->bf16 RNE
// cast + 16x16x32 bf16 MFMA (fp32 accum). K=128 fits entirely in LDS -> no
// global K-loop. 128x128 tile, 4 waves of 64x64, XOR-swizzled LDS (64 KB).

#define NEXP 8
#define NROW 4096
#define KD   128
#define NOUT 4096
#define TILE 128

typedef __attribute__((ext_vector_type(8))) short bf16x8;
typedef __attribute__((ext_vector_type(4))) float f32x4;

// Pack two fp32 into two bf16 (round-to-nearest-even) in one uint.
__device__ __forceinline__ unsigned int pack2_bf16(float lo, float hi) {
  unsigned int ulo = __float_as_uint(lo);
  ulo += 0x7fffu + ((ulo >> 16) & 1u);
  unsigned int uhi = __float_as_uint(hi);
  uhi += 0x7fffu + ((uhi >> 16) & 1u);
  return (ulo >> 16) | (uhi & 0xffff0000u);
}

__global__ __launch_bounds__(256, 2)
void moe_gemm_bf16(const float* __restrict__ X, const float* __restrict__ W,
                   float* __restrict__ Out) {
  // Row-major [row][k] bf16 tiles, with 16B-chunk XOR swizzle:
  // chunk index cs = c ^ (row & 15). Row stride = 256 B (0 mod 32 banks), so
  // without swizzle a quad's 16 lanes would hit the same 4 banks (16-way
  // conflict). Swizzle spreads them across all 8 bank groups. LDS = 64 KB
  // exactly (2 blocks/CU) — padding instead would exceed the static limit.
  __shared__ unsigned short As[TILE * KD];
  __shared__ unsigned short Bs[TILE * KD];

  const int e    = blockIdx.z;
  const int row0 = blockIdx.y * TILE;
  const int col0 = blockIdx.x * TILE;
  const int t    = threadIdx.x;

  const float* xg = X + ((size_t)e * NROW + row0) * KD;
  const float* wg = W + ((size_t)e * NOUT + col0) * KD;

  // Stage: 16384 floats each for A and B. 256 thr x 8 rounds x 8 floats.
  // Per thread-round: 32B contiguous global read, convert, one b128 LDS write.
#pragma unroll
  for (int r = 0; r < 8; ++r) {
    const int flat = r * 2048 + t * 8;     // 8-float chunk, never crosses a row
    const int row  = flat >> 7;
    const int c    = (flat >> 3) & 15;     // 16B chunk within row
    const int cs   = c ^ (row & 15);
    const int lidx = row * KD + cs * 8;    // ushort index

    float4 a0 = *(const float4*)(xg + flat);
    float4 a1 = *(const float4*)(xg + flat + 4);
    float4 b0 = *(const float4*)(wg + flat);
    float4 b1 = *(const float4*)(wg + flat + 4);

    uint4 ap, bp;
    ap.x = pack2_bf16(a0.x, a0.y); ap.y = pack2_bf16(a0.z, a0.w);
    ap.z = pack2_bf16(a1.x, a1.y); ap.w = pack2_bf16(a1.z, a1.w);
    bp.x = pack2_bf16(b0.x, b0.y); bp.y = pack2_bf16(b0.z, b0.w);
    bp.z = pack2_bf16(b1.x, b1.y); bp.w = pack2_bf16(b1.z, b1.w);

    *(uint4*)(&As[lidx]) = ap;
    *(uint4*)(&Bs[lidx]) = bp;
  }
  __syncthreads();

  const int lane = t & 63;
  const int wave = t >> 6;
  const int quad = lane >> 4;
  const int l16  = lane & 15;
  const int wm   = (wave & 1) * 64;   // wave's row offset in tile
  const int wn   = (wave >> 1) * 64;  // wave's col offset in tile

  f32x4 acc[4][4];
#pragma unroll
  for (int i = 0; i < 4; ++i)
#pragma unroll
    for (int j = 0; j < 4; ++j)
      acc[i][j] = (f32x4)(0.0f);

  // K = 128 = 4 steps of 32. A-frag: lane holds A[m=l16][k = quad*8 + 0..7].
#pragma unroll
  for (int ks = 0; ks < 4; ++ks) {
    const int c  = ks * 4 + quad;       // 16B chunk index along k
    const int cs = c ^ l16;             // (row & 15) == l16 for all frags
    bf16x8 av[4], bv[4];
#pragma unroll
    for (int i = 0; i < 4; ++i) {
      const int row = wm + i * 16 + l16;
      av[i] = *(const bf16x8*)(&As[row * KD + cs * 8]);
    }
#pragma unroll
    for (int j = 0; j < 4; ++j) {
      const int row = wn + j * 16 + l16;
      bv[j] = *(const bf16x8*)(&Bs[row * KD + cs * 8]);
    }
#pragma unroll
    for (int i = 0; i < 4; ++i)
#pragma unroll
      for (int j = 0; j < 4; ++j)
        acc[i][j] = __builtin_amdgcn_mfma_f32_16x16x32_bf16(av[i], bv[j],
                                                            acc[i][j], 0, 0, 0);
  }

  // Epilogue: C/D layout col = l16, row = quad*4 + v (verified gemm_bt map).
  float* og = Out + ((size_t)e * NROW + row0 + wm + quad * 4) * NOUT
                  + col0 + wn + l16;
#pragma unroll
  for (int i = 0; i < 4; ++i)
#pragma unroll
    for (int v = 0; v < 4; ++v) {
      float* orow = og + (size_t)(i * 16 + v) * NOUT;
#pragma unroll
      for (int j = 0; j < 4; ++j)
        orow[j * 16] = acc[i][j][v];
    }
}

extern "C" void kernel_launch(void* const* d_in, const int* in_sizes, int n_in,
                              void* d_out, int out_size, void* d_ws, size_t ws_size,
                              hipStream_t stream) {
  const float* X = (const float*)d_in[0];
  const float* W = (const float*)d_in[1];
  float* Out = (float*)d_out;
  dim3 grid(NOUT / TILE, NROW / TILE, NEXP);  // (32, 32, 8)
  moe_gemm_bf16<<<grid, dim3(256, 1, 1), 0, stream>>>(X, W, Out);
}

// Round 2
// 597.248 us; speedup vs baseline: 1.0400x; 1.0400x over previous
//
#include <hip/hip_runtime.h>
#include <hip/hip_bf16.h>

// Grouped GEMM: out[e] = x[e] @ W[e]^T
//   x: [8, 4096, 128] fp32, W: [8, 4096, 128] fp32 -> out: [8, 4096, 4096] fp32
// Write-bound (537 MB out vs 34.4 GFLOP). In-kernel fp32->bf16 RNE cast +
// 16x16x32 bf16 MFMA (fp32 accum). K=128 entirely in LDS -> no global K-loop.
//
// R1 -> R2: 256thr/4waves -> 512thr/8waves per 128x128 tile. Per-wave regs:
// acc 64->32 AGPR, staging unroll 8->4 rounds. __launch_bounds__(512,4) caps
// VGPR<=128 so occupancy = 2 blocks/CU (LDS 64KB) x 8 waves = 16 waves/CU
// (50%), vs 8 waves/CU before. Output stores nontemporal (never re-read).

#define NEXP 8
#define NROW 4096
#define KD   128
#define NOUT 4096
#define TILE 128

typedef __attribute__((ext_vector_type(8))) short bf16x8;
typedef __attribute__((ext_vector_type(4))) float f32x4;

// Pack two fp32 into two bf16 (round-to-nearest-even) in one uint.
__device__ __forceinline__ unsigned int pack2_bf16(float lo, float hi) {
  unsigned int ulo = __float_as_uint(lo);
  ulo += 0x7fffu + ((ulo >> 16) & 1u);
  unsigned int uhi = __float_as_uint(hi);
  uhi += 0x7fffu + ((uhi >> 16) & 1u);
  return (ulo >> 16) | (uhi & 0xffff0000u);
}

__global__ __launch_bounds__(512, 4)
void moe_gemm_bf16(const float* __restrict__ X, const float* __restrict__ W,
                   float* __restrict__ Out) {
  // Row-major [row][k] bf16 tiles, 16B-chunk XOR swizzle (cs = c ^ (row&15)).
  // Row stride 256 B == 0 mod 32 banks; swizzle spreads quads across all bank
  // groups. 64 KB total -> 2 blocks/CU.
  __shared__ unsigned short As[TILE * KD];
  __shared__ unsigned short Bs[TILE * KD];

  const int e    = blockIdx.z;
  const int row0 = blockIdx.y * TILE;
  const int col0 = blockIdx.x * TILE;
  const int t    = threadIdx.x;

  const float* xg = X + ((size_t)e * NROW + row0) * KD;
  const float* wg = W + ((size_t)e * NOUT + col0) * KD;

  // Stage 16384 floats per matrix: 512 thr x 4 rounds x 8 floats.
#pragma unroll
  for (int r = 0; r < 4; ++r) {
    const int flat = r * 4096 + t * 8;     // 8-float chunk, never crosses a row
    const int row  = flat >> 7;
    const int c    = (flat >> 3) & 15;     // 16B chunk within row
    const int cs   = c ^ (row & 15);
    const int lidx = row * KD + cs * 8;    // ushort index

    float4 a0 = *(const float4*)(xg + flat);
    float4 a1 = *(const float4*)(xg + flat + 4);
    float4 b0 = *(const float4*)(wg + flat);
    float4 b1 = *(const float4*)(wg + flat + 4);

    uint4 ap, bp;
    ap.x = pack2_bf16(a0.x, a0.y); ap.y = pack2_bf16(a0.z, a0.w);
    ap.z = pack2_bf16(a1.x, a1.y); ap.w = pack2_bf16(a1.z, a1.w);
    bp.x = pack2_bf16(b0.x, b0.y); bp.y = pack2_bf16(b0.z, b0.w);
    bp.z = pack2_bf16(b1.x, b1.y); bp.w = pack2_bf16(b1.z, b1.w);

    *(uint4*)(&As[lidx]) = ap;
    *(uint4*)(&Bs[lidx]) = bp;
  }
  __syncthreads();

  const int lane = t & 63;
  const int wave = t >> 6;          // 0..7
  const int quad = lane >> 4;
  const int l16  = lane & 15;
  const int wm   = (wave & 1) * 64;   // wave's row offset in tile (2 in M)
  const int wn   = (wave >> 1) * 32;  // wave's col offset in tile (4 in N)

  f32x4 acc[4][2];
#pragma unroll
  for (int i = 0; i < 4; ++i)
#pragma unroll
    for (int j = 0; j < 2; ++j)
      acc[i][j] = (f32x4)(0.0f);

  // K = 128 = 4 steps of 32. A-frag: lane holds A[m=l16][k = quad*8 + 0..7].
#pragma unroll
  for (int ks = 0; ks < 4; ++ks) {
    const int c  = ks * 4 + quad;       // 16B chunk index along k
    const int cs = c ^ l16;             // (row & 15) == l16 for all frag rows
    bf16x8 av[4], bv[2];
#pragma unroll
    for (int i = 0; i < 4; ++i) {
      const int row = wm + i * 16 + l16;
      av[i] = *(const bf16x8*)(&As[row * KD + cs * 8]);
    }
#pragma unroll
    for (int j = 0; j < 2; ++j) {
      const int row = wn + j * 16 + l16;
      bv[j] = *(const bf16x8*)(&Bs[row * KD + cs * 8]);
    }
#pragma unroll
    for (int i = 0; i < 4; ++i)
#pragma unroll
      for (int j = 0; j < 2; ++j)
        acc[i][j] = __builtin_amdgcn_mfma_f32_16x16x32_bf16(av[i], bv[j],
                                                            acc[i][j], 0, 0, 0);
  }

  // Epilogue: C/D layout col = l16, row = quad*4 + v (verified gemm_bt map).
  // Output is never re-read -> nontemporal stores, keep L2 for tile re-reads.
  float* og = Out + ((size_t)e * NROW + row0 + wm + quad * 4) * NOUT
                  + col0 + wn + l16;
#pragma unroll
  for (int i = 0; i < 4; ++i)
#pragma unroll
    for (int v = 0; v < 4; ++v) {
      float* orow = og + (size_t)(i * 16 + v) * NOUT;
#pragma unroll
      for (int j = 0; j < 2; ++j)
        __builtin_nontemporal_store(acc[i][j][v], orow + j * 16);
    }
}

extern "C" void kernel_launch(void* const* d_in, const int* in_sizes, int n_in,
                              void* d_out, int out_size, void* d_ws, size_t ws_size,
                              hipStream_t stream) {
  const float* X = (const float*)d_in[0];
  const float* W = (const float*)d_in[1];
  float* Out = (float*)d_out;
  dim3 grid(NOUT / TILE, NROW / TILE, NEXP);  // (32, 32, 8)
  moe_gemm_bf16<<<grid, dim3(512, 1, 1), 0, stream>>>(X, W, Out);
}